// Round 7
// baseline (239.870 us; speedup 1.0000x reference)
//
#include <hip/hip_runtime.h>
#include <type_traits>

typedef _Float16 f16;
typedef _Float16 f16x4 __attribute__((ext_vector_type(4)));
typedef _Float16 f16x8 __attribute__((ext_vector_type(8)));
typedef float f32x4 __attribute__((ext_vector_type(4)));

constexpr int SP = 65536;  // 16^4

template<int V> using IC = std::integral_constant<int, V>;

#define GLD16(g, l) __builtin_amdgcn_global_load_lds( \
  (const __attribute__((address_space(1))) void*)(g), \
  (__attribute__((address_space(3))) void*)(l), 16, 0, 0)

// ---------------------------------------------------------------------------
// ws layout (half-element offsets):
//   w1t   [0, 3072)         32*96   (layer1: [co][tap-padded-96])
//   w2t   [3072, 168960)    81*64*32  [tap][co][ci]
//   w3t   [168960, 334848)  81*32*64
//   w4t   [334848, 376320)  81*16*32
//   zpage [376320, 376448)  zeros (OOB GLD source)
//   a1    [376448, +2*SP*32)  channels-last f16
//   a2    a1 + 4194304, 2*SP*64;  a3 aliases a1
// ---------------------------------------------------------------------------
__global__ __launch_bounds__(256) void wtrans_k(
    const float* __restrict__ w1, const float* __restrict__ w2,
    const float* __restrict__ w3, const float* __restrict__ w4,
    f16* __restrict__ wt)
{
  int i = blockIdx.x * 256 + threadIdx.x;
  if (i < 3072) {
    int co = i / 96, k = i - co * 96;
    wt[i] = (k < 81) ? (f16)w1[co * 81 + k] : (f16)0.f;
  } else if (i < 168960) {
    int j = i - 3072;
    int t = j >> 11, r = j & 2047;
    int co = r >> 5, ci = r & 31;
    wt[i] = (f16)w2[(co * 32 + ci) * 81 + t];
  } else if (i < 334848) {
    int j = i - 168960;
    int t = j >> 11, r = j & 2047;
    int co = r >> 6, ci = r & 63;
    wt[i] = (f16)w3[(co * 64 + ci) * 81 + t];
  } else if (i < 376320) {
    int j = i - 334848;
    int t = j >> 9, r = j & 511;
    int co = r >> 5, ci = r & 31;
    wt[i] = (co == 0) ? (f16)w4[ci * 81 + t] : (f16)0.f;
  } else if (i < 376448) {
    wt[i] = (f16)0.f;                 // zero page
  }
}

// 512-block XCD swizzle: verified FETCH 132MB -> 12.6MB.
__device__ inline int xcd_swizzle512(int raw) { return (raw & 7) * 64 + (raw >> 3); }

// ---------------------------------------------------------------------------
// Layer 1: Cin=1, Cout=32, fp32 in -> f16 channels-last out. (unchanged)
// ---------------------------------------------------------------------------
__global__ __launch_bounds__(256) void conv_l1_k(
    const float* __restrict__ x, const f16* __restrict__ w1t,
    const float* __restrict__ bias, f16* __restrict__ aout)
{
  __shared__ float H1[9 * 324];
  __shared__ f16 Bexp[256 * 104];
  const int tid = threadIdx.x;
  const int bid = xcd_swizzle512(blockIdx.x);
  const int b = bid >> 8;
  const int d1 = (bid >> 4) & 15, d2 = bid & 15;
  const float* xb = x + b * SP;

  for (int idx = tid; idx < 9 * 324; idx += 256) {
    int e = idx / 324, c = idx - e * 324;
    int h3 = c / 18, h4 = c - h3 * 18;
    int e1 = e / 3, e2 = e - e1 * 3;
    int dd1 = d1 + e1 - 1, dd2 = d2 + e2 - 1;
    int dd3 = h3 - 1, dd4 = h4 - 1;
    float v = 0.f;
    if (((unsigned)dd1 < 16u) & ((unsigned)dd2 < 16u) &
        ((unsigned)dd3 < 16u) & ((unsigned)dd4 < 16u))
      v = xb[((dd1 * 16 + dd2) * 16 + dd3) * 16 + dd4];
    H1[idx] = v;
  }
  __syncthreads();
  {
    int d3 = tid >> 4, d4 = tid & 15;
    f16* bp = Bexp + tid * 104;
    #pragma unroll
    for (int k = 0; k < 96; ++k) {
      float v = 0.f;
      if (k < 81) {
        int e = k / 9, rem = k - e * 9;
        int o3 = rem / 3, o4 = rem - o3 * 3;
        v = H1[e * 324 + (d3 + o3) * 18 + (d4 + o4)];
      }
      bp[k] = (f16)v;
    }
  }
  __syncthreads();

  const int lane = tid & 63, wave = tid >> 6;
  const int lm = lane & 15, kp = lane >> 4;
  f32x4 acc[2][4] = {};
  #pragma unroll
  for (int k0 = 0; k0 < 96; k0 += 32) {
    f16x8 a0 = *(const f16x8*)(w1t + lm * 96 + k0 + kp * 8);
    f16x8 a1 = *(const f16x8*)(w1t + (16 + lm) * 96 + k0 + kp * 8);
    #pragma unroll
    for (int nt = 0; nt < 4; ++nt) {
      int n = (wave * 4 + nt) * 16 + lm;
      f16x8 bf = *(const f16x8*)(Bexp + n * 104 + k0 + kp * 8);
      acc[0][nt] = __builtin_amdgcn_mfma_f32_16x16x32_f16(a0, bf, acc[0][nt], 0, 0, 0);
      acc[1][nt] = __builtin_amdgcn_mfma_f32_16x16x32_f16(a1, bf, acc[1][nt], 0, 0, 0);
    }
  }
  #pragma unroll
  for (int mt = 0; mt < 2; ++mt) {
    int co = mt * 16 + kp * 4;
    const float* bp = bias + co;
    #pragma unroll
    for (int nt = 0; nt < 4; ++nt) {
      int d3 = wave * 4 + nt;
      f16x4 pk;
      #pragma unroll
      for (int r = 0; r < 4; ++r)
        pk[r] = (f16)fmaxf(acc[mt][nt][r] + bp[r], 0.f);
      *(f16x4*)(aout + (bid * 256 + d3 * 16 + lm) * 32 + co) = pk;
    }
  }
}

// ---------------------------------------------------------------------------
// Layers 2..4: full-plane 4-wave blocks, lockstep stages (weights L1-shared
// across the CU), halo-only dbuf LDS via GLD16, ONE barrier/stage with the
// counted-vmcnt BEFORE it (drain own GLD(s) pre-barrier -> after barrier all
// waves' DMA visible; next-stage GLDs + A-prefetch stay in flight).
// A-fragments register-pipelined one o3-group ahead, compile-time set parity
// (stage-pair unroll). Wave w owns d3-rows 4w..4w+3 (nt=4). Per stage:
// 9 (o3,o4) x 4 nt x MT MFMA; B = 1 ds_read_b128 per (o3,o4,nt).
// VMEM queue/stage (per wave): [GLD(s) x6 (oldest), A(s,g0) x3MT] ->
// vmcnt(3*MT) drains exactly GLD(s).
// ---------------------------------------------------------------------------
template<int CIN, int COUTP, bool RELU, bool FINAL, int WPE>
__global__ __launch_bounds__(256, WPE) void conv_plane_k(
    const f16* __restrict__ ain, const f16* __restrict__ wt,
    const float* __restrict__ bias, const f16* __restrict__ zpage,
    f16* __restrict__ aout, float* __restrict__ fout)
{
  constexpr int MT = COUTP / 16;
  constexpr int NCK = CIN / 32;
  constexpr int NSTAGE = NCK * 9;
  constexpr int BUFH = 384 * 32;         // halves = 24,576 B (324 cells + pad)
  __shared__ f16 hal[2 * BUFH];          // 49,152 B -> 3 blocks/CU

  const int tid = threadIdx.x, lane = tid & 63, wave = tid >> 6;
  const int plane = xcd_swizzle512(blockIdx.x);
  const int b = plane >> 8, d1 = (plane >> 4) & 15, d2 = plane & 15;
  const int lm = lane & 15, kp = lane >> 4;

  f32x4 acc[MT][4] = {};
  f16x8 A[2][3 * MT];

  auto issue_halo = [&](int s) {
    int ck = (NCK == 2 && s >= 9) ? 1 : 0;
    int e = s - ck * 9;
    int e1 = e / 3, e2 = e - e1 * 3;
    int dd1 = d1 + e1 - 1, dd2 = d2 + e2 - 1;
    bool pok = ((unsigned)dd1 < 16u) & ((unsigned)dd2 < 16u);
    const f16* pbase = ain + ((size_t)((b * 16 + dd1) * 16 + dd2) * 256) * CIN + ck * 32;
    f16* dst0 = hal + (s & 1) * BUFH;
    #pragma unroll
    for (int j = 0; j < 6; ++j) {
      int u = j * 256 + wave * 64 + lane;        // 16B-unit, 1536 slots/buffer
      int cell = u >> 2, q = u & 3;
      int h3 = cell / 18, h4 = cell - h3 * 18;
      int dd3 = h3 - 1, dd4 = h4 - 1;
      bool ok = pok & (cell < 324) & ((unsigned)dd3 < 16u) & ((unsigned)dd4 < 16u);
      const f16* src = ok ? (pbase + (size_t)(dd3 * 16 + dd4) * CIN + q * 8) : zpage;
      GLD16(src, dst0 + (j * 256 + wave * 64) * 8);   // wave-uniform base
    }
  };

  // Load A-group (sg, gg) = taps e*9 + gg*3 + {0,1,2} into register set SET.
  auto load_A = [&](int sg, int gg, auto SetC) {
    constexpr int SET = decltype(SetC)::value;
    int ck = (NCK == 2 && sg >= 9) ? 1 : 0;
    int e = sg - ck * 9;
    const f16* wb = wt + ((size_t)(e * 9 + gg * 3) * COUTP + lm) * CIN + ck * 32 + kp * 8;
    #pragma unroll
    for (int t = 0; t < 3; ++t)
      #pragma unroll
      for (int mt = 0; mt < MT; ++mt)
        A[SET][t * MT + mt] = *(const f16x8*)(wb + (size_t)(t * COUTP + mt * 16) * CIN);
  };

  auto group_compute = [&](const f16* buf, int g, auto SetC) {
    constexpr int SET = decltype(SetC)::value;
    #pragma unroll
    for (int o4 = 0; o4 < 3; ++o4)
      #pragma unroll
      for (int nt = 0; nt < 4; ++nt) {
        int cell = (wave * 4 + nt + g) * 18 + lm + o4;
        f16x8 bf = *(const f16x8*)(buf + cell * 32 + kp * 8);
        #pragma unroll
        for (int mt = 0; mt < MT; ++mt)
          acc[mt][nt] = __builtin_amdgcn_mfma_f32_16x16x32_f16(
              A[SET][o4 * MT + mt], bf, acc[mt][nt], 0, 0, 0);
      }
  };

  auto stage = [&](int s, auto Pc) {
    constexpr int P = decltype(Pc)::value;
    // Drain own GLD(s) (oldest 6); keep A(s,g0) (3*MT newest) in flight.
    if constexpr (MT == 4)      asm volatile("s_waitcnt vmcnt(12)" ::: "memory");
    else if constexpr (MT == 2) asm volatile("s_waitcnt vmcnt(6)"  ::: "memory");
    else                        asm volatile("s_waitcnt vmcnt(3)"  ::: "memory");
    __builtin_amdgcn_s_barrier();          // now buf[s&1] fully staged, all waves
    if (s + 1 < NSTAGE) issue_halo(s + 1); // safe: buf[s+1&1] closed by barrier
    const f16* buf = hal + (s & 1) * BUFH;
    // g = 0: consume set P, prefetch (s,1) -> set (1+P)&1
    load_A(s, 1, IC<(1 + P) & 1>{});
    group_compute(buf, 0, IC<P>{});
    // g = 1: consume set (1+P)&1, prefetch (s,2) -> set P
    load_A(s, 2, IC<P>{});
    group_compute(buf, 1, IC<(1 + P) & 1>{});
    // g = 2: consume set P, prefetch (s+1,0) -> set (1+P)&1
    if (s + 1 < NSTAGE) load_A(s + 1, 0, IC<(1 + P) & 1>{});
    group_compute(buf, 2, IC<P>{});
  };

  issue_halo(0);
  load_A(0, 0, IC<0>{});
  int s = 0;
  for (; s + 1 < NSTAGE; s += 2) {
    stage(s, IC<0>{});
    stage(s + 1, IC<1>{});
  }
  if (s < NSTAGE) stage(s, IC<0>{});

  // ---- epilogue ----
  if (FINAL) {
    if (kp == 0) {
      float bv = bias[0];
      #pragma unroll
      for (int nt = 0; nt < 4; ++nt) {
        int r = wave * 4 + nt;
        fout[plane * 256 + r * 16 + lm] = acc[0][nt][0] + bv;
      }
    }
  } else {
    #pragma unroll
    for (int mt = 0; mt < MT; ++mt) {
      int co = mt * 16 + kp * 4;
      const float* bp = bias + co;
      #pragma unroll
      for (int nt = 0; nt < 4; ++nt) {
        int r = wave * 4 + nt;
        f16x4 pk;
        #pragma unroll
        for (int q = 0; q < 4; ++q) {
          float v = acc[mt][nt][q] + bp[q];
          if (RELU) v = fmaxf(v, 0.f);
          pk[q] = (f16)v;
        }
        *(f16x4*)(aout + ((size_t)(plane * 256 + r * 16 + lm)) * COUTP + co) = pk;
      }
    }
  }
}

extern "C" void kernel_launch(void* const* d_in, const int* in_sizes, int n_in,
                              void* d_out, int out_size, void* d_ws, size_t ws_size,
                              hipStream_t stream)
{
  (void)in_sizes; (void)n_in; (void)out_size; (void)ws_size;
  const float* x  = (const float*)d_in[0];
  const float* w1 = (const float*)d_in[1];
  const float* b1 = (const float*)d_in[2];
  const float* w2 = (const float*)d_in[3];
  const float* b2 = (const float*)d_in[4];
  const float* w3 = (const float*)d_in[5];
  const float* b3 = (const float*)d_in[6];
  const float* w4 = (const float*)d_in[7];
  const float* b4 = (const float*)d_in[8];

  f16* ws  = (f16*)d_ws;
  f16* w1t = ws;
  f16* w2t = ws + 3072;
  f16* w3t = ws + 168960;
  f16* w4t = ws + 334848;
  f16* zpg = ws + 376320;
  f16* a1  = ws + 376448;
  f16* a2  = a1 + (size_t)2 * SP * 32;
  f16* a3  = a1;                      // a1 dead after layer 2 reads it
  float* out = (float*)d_out;

  wtrans_k<<<1471, 256, 0, stream>>>(w1, w2, w3, w4, ws);
  conv_l1_k<<<512, 256, 0, stream>>>(x, w1t, b1, a1);
  conv_plane_k<32, 64, true,  false, 2><<<512, 256, 0, stream>>>(a1, w2t, b2, zpg, a2, nullptr);
  conv_plane_k<64, 32, true,  false, 3><<<512, 256, 0, stream>>>(a2, w3t, b3, zpg, a3, nullptr);
  conv_plane_k<32, 16, false, true,  3><<<512, 256, 0, stream>>>(a3, w4t, b4, zpg, nullptr, out);
}

// Round 8
// 237.191 us; speedup vs baseline: 1.0113x; 1.0113x over previous
//
#include <hip/hip_runtime.h>
#include <type_traits>

typedef _Float16 f16;
typedef _Float16 f16x4 __attribute__((ext_vector_type(4)));
typedef _Float16 f16x8 __attribute__((ext_vector_type(8)));
typedef float f32x4 __attribute__((ext_vector_type(4)));

constexpr int SP = 65536;  // 16^4

template<int V> using IC = std::integral_constant<int, V>;

#define GLD16(g, l) __builtin_amdgcn_global_load_lds( \
  (const __attribute__((address_space(1))) void*)(g), \
  (__attribute__((address_space(3))) void*)(l), 16, 0, 0)

// ---------------------------------------------------------------------------
// ws layout (half-element offsets):
//   w1t   [0, 3072)         32*96   (layer1: [co][tap-padded-96])
//   w2t   [3072, 168960)    81*64*32  [tap][co][ci]
//   w3t   [168960, 334848)  81*32*64
//   w4t   [334848, 376320)  81*16*32
//   zpage [376320, 376448)  zeros (OOB GLD source)
//   a1    [376448, +2*SP*32)  channels-last f16
//   a2    a1 + 4194304, 2*SP*64;  a3 aliases a1
// ---------------------------------------------------------------------------
__global__ __launch_bounds__(256) void wtrans_k(
    const float* __restrict__ w1, const float* __restrict__ w2,
    const float* __restrict__ w3, const float* __restrict__ w4,
    f16* __restrict__ wt)
{
  int i = blockIdx.x * 256 + threadIdx.x;
  if (i < 3072) {
    int co = i / 96, k = i - co * 96;
    wt[i] = (k < 81) ? (f16)w1[co * 81 + k] : (f16)0.f;
  } else if (i < 168960) {
    int j = i - 3072;
    int t = j >> 11, r = j & 2047;
    int co = r >> 5, ci = r & 31;
    wt[i] = (f16)w2[(co * 32 + ci) * 81 + t];
  } else if (i < 334848) {
    int j = i - 168960;
    int t = j >> 11, r = j & 2047;
    int co = r >> 6, ci = r & 63;
    wt[i] = (f16)w3[(co * 64 + ci) * 81 + t];
  } else if (i < 376320) {
    int j = i - 334848;
    int t = j >> 9, r = j & 511;
    int co = r >> 5, ci = r & 31;
    wt[i] = (co == 0) ? (f16)w4[ci * 81 + t] : (f16)0.f;
  } else if (i < 376448) {
    wt[i] = (f16)0.f;                 // zero page
  }
}

// 512-block XCD swizzle: verified FETCH 132MB -> 12.6MB.
__device__ inline int xcd_swizzle512(int raw) { return (raw & 7) * 64 + (raw >> 3); }

// ---------------------------------------------------------------------------
// Layer 1: Cin=1, Cout=32, fp32 in -> f16 channels-last out. (unchanged)
// ---------------------------------------------------------------------------
__global__ __launch_bounds__(256) void conv_l1_k(
    const float* __restrict__ x, const f16* __restrict__ w1t,
    const float* __restrict__ bias, f16* __restrict__ aout)
{
  __shared__ float H1[9 * 324];
  __shared__ f16 Bexp[256 * 104];
  const int tid = threadIdx.x;
  const int bid = xcd_swizzle512(blockIdx.x);
  const int b = bid >> 8;
  const int d1 = (bid >> 4) & 15, d2 = bid & 15;
  const float* xb = x + b * SP;

  for (int idx = tid; idx < 9 * 324; idx += 256) {
    int e = idx / 324, c = idx - e * 324;
    int h3 = c / 18, h4 = c - h3 * 18;
    int e1 = e / 3, e2 = e - e1 * 3;
    int dd1 = d1 + e1 - 1, dd2 = d2 + e2 - 1;
    int dd3 = h3 - 1, dd4 = h4 - 1;
    float v = 0.f;
    if (((unsigned)dd1 < 16u) & ((unsigned)dd2 < 16u) &
        ((unsigned)dd3 < 16u) & ((unsigned)dd4 < 16u))
      v = xb[((dd1 * 16 + dd2) * 16 + dd3) * 16 + dd4];
    H1[idx] = v;
  }
  __syncthreads();
  {
    int d3 = tid >> 4, d4 = tid & 15;
    f16* bp = Bexp + tid * 104;
    #pragma unroll
    for (int k = 0; k < 96; ++k) {
      float v = 0.f;
      if (k < 81) {
        int e = k / 9, rem = k - e * 9;
        int o3 = rem / 3, o4 = rem - o3 * 3;
        v = H1[e * 324 + (d3 + o3) * 18 + (d4 + o4)];
      }
      bp[k] = (f16)v;
    }
  }
  __syncthreads();

  const int lane = tid & 63, wave = tid >> 6;
  const int lm = lane & 15, kp = lane >> 4;
  f32x4 acc[2][4] = {};
  #pragma unroll
  for (int k0 = 0; k0 < 96; k0 += 32) {
    f16x8 a0 = *(const f16x8*)(w1t + lm * 96 + k0 + kp * 8);
    f16x8 a1 = *(const f16x8*)(w1t + (16 + lm) * 96 + k0 + kp * 8);
    #pragma unroll
    for (int nt = 0; nt < 4; ++nt) {
      int n = (wave * 4 + nt) * 16 + lm;
      f16x8 bf = *(const f16x8*)(Bexp + n * 104 + k0 + kp * 8);
      acc[0][nt] = __builtin_amdgcn_mfma_f32_16x16x32_f16(a0, bf, acc[0][nt], 0, 0, 0);
      acc[1][nt] = __builtin_amdgcn_mfma_f32_16x16x32_f16(a1, bf, acc[1][nt], 0, 0, 0);
    }
  }
  #pragma unroll
  for (int mt = 0; mt < 2; ++mt) {
    int co = mt * 16 + kp * 4;
    const float* bp = bias + co;
    #pragma unroll
    for (int nt = 0; nt < 4; ++nt) {
      int d3 = wave * 4 + nt;
      f16x4 pk;
      #pragma unroll
      for (int r = 0; r < 4; ++r)
        pk[r] = (f16)fmaxf(acc[mt][nt][r] + bp[r], 0.f);
      *(f16x4*)(aout + (bid * 256 + d3 * 16 + lm) * 32 + co) = pk;
    }
  }
}

// ---------------------------------------------------------------------------
// Layers 2..4: full-plane 4-wave lockstep blocks, halo dbuf via GLD16.
// Round-8 fixes (r3..r7 all plateaued 91-97us, every pipe idle -> exposed
// per-pair LDS latency + halo queue entanglement):
//  (1) B-fragments of each o3-group hoisted into 12 named regs BEFORE the
//      group's MFMAs -> one counted lgkm bubble/group, not 12.
//  (2) issue_halo(s+1) moved AFTER load_A(s,2): VMEM queue per stage is
//      [halo(s)][A(s,0)] | entry vmcnt(6) drains halo(s) only |
//      [A(s,1)][A(s,2)][halo(s+1)][A(s+1,0)] -> g0/g1 A-waits touch only
//      A-loads; g2's vmcnt(12) keeps halo(s+1) in flight; next stage entry
//      drains it exactly when it must be complete.
// A double-set register pipelined (compile-time parity, stage-pair unroll).
// ---------------------------------------------------------------------------
template<int CIN, int COUTP, bool RELU, bool FINAL, int WPE>
__global__ __launch_bounds__(256, WPE) void conv_plane_k(
    const f16* __restrict__ ain, const f16* __restrict__ wt,
    const float* __restrict__ bias, const f16* __restrict__ zpage,
    f16* __restrict__ aout, float* __restrict__ fout)
{
  constexpr int MT = COUTP / 16;
  constexpr int NCK = CIN / 32;
  constexpr int NSTAGE = NCK * 9;
  constexpr int BUFH = 384 * 32;         // halves = 24,576 B
  __shared__ f16 hal[2 * BUFH];          // 49,152 B

  const int tid = threadIdx.x, lane = tid & 63, wave = tid >> 6;
  const int plane = xcd_swizzle512(blockIdx.x);
  const int b = plane >> 8, d1 = (plane >> 4) & 15, d2 = plane & 15;
  const int lm = lane & 15, kp = lane >> 4;

  f32x4 acc[MT][4] = {};
  f16x8 A[2][3 * MT];

  auto issue_halo = [&](int s) {
    int ck = (NCK == 2 && s >= 9) ? 1 : 0;
    int e = s - ck * 9;
    int e1 = e / 3, e2 = e - e1 * 3;
    int dd1 = d1 + e1 - 1, dd2 = d2 + e2 - 1;
    bool pok = ((unsigned)dd1 < 16u) & ((unsigned)dd2 < 16u);
    const f16* pbase = ain + ((size_t)((b * 16 + dd1) * 16 + dd2) * 256) * CIN + ck * 32;
    f16* dst0 = hal + (s & 1) * BUFH;
    #pragma unroll
    for (int j = 0; j < 6; ++j) {
      int u = j * 256 + wave * 64 + lane;        // 16B-unit, 1536 slots/buffer
      int cell = u >> 2, q = u & 3;
      int h3 = cell / 18, h4 = cell - h3 * 18;
      int dd3 = h3 - 1, dd4 = h4 - 1;
      bool ok = pok & (cell < 324) & ((unsigned)dd3 < 16u) & ((unsigned)dd4 < 16u);
      const f16* src = ok ? (pbase + (size_t)(dd3 * 16 + dd4) * CIN + q * 8) : zpage;
      GLD16(src, dst0 + (j * 256 + wave * 64) * 8);   // wave-uniform base
    }
  };

  auto load_A = [&](int sg, int gg, auto SetC) {
    constexpr int SET = decltype(SetC)::value;
    int ck = (NCK == 2 && sg >= 9) ? 1 : 0;
    int e = sg - ck * 9;
    const f16* wb = wt + ((size_t)(e * 9 + gg * 3) * COUTP + lm) * CIN + ck * 32 + kp * 8;
    #pragma unroll
    for (int t = 0; t < 3; ++t)
      #pragma unroll
      for (int mt = 0; mt < MT; ++mt)
        A[SET][t * MT + mt] = *(const f16x8*)(wb + (size_t)(t * COUTP + mt * 16) * CIN);
  };

  auto group_compute = [&](const f16* buf, int g, auto SetC) {
    constexpr int SET = decltype(SetC)::value;
    f16x8 bf[12];                        // hoisted group B: 12 ds_read_b128
    #pragma unroll
    for (int o4 = 0; o4 < 3; ++o4)
      #pragma unroll
      for (int nt = 0; nt < 4; ++nt)
        bf[o4 * 4 + nt] = *(const f16x8*)(buf + ((wave * 4 + nt + g) * 18 + lm + o4) * 32 + kp * 8);
    #pragma unroll
    for (int o4 = 0; o4 < 3; ++o4)
      #pragma unroll
      for (int nt = 0; nt < 4; ++nt)
        #pragma unroll
        for (int mt = 0; mt < MT; ++mt)
          acc[mt][nt] = __builtin_amdgcn_mfma_f32_16x16x32_f16(
              A[SET][o4 * MT + mt], bf[o4 * 4 + nt], acc[mt][nt], 0, 0, 0);
  };

  auto stage = [&](int s, auto Pc) {
    constexpr int P = decltype(Pc)::value;
    // queue here: [halo(s) x6 oldest][A(s,0) x3MT] -> drain exactly halo(s)
    if constexpr (MT == 4)      asm volatile("s_waitcnt vmcnt(12)" ::: "memory");
    else if constexpr (MT == 2) asm volatile("s_waitcnt vmcnt(6)"  ::: "memory");
    else                        asm volatile("s_waitcnt vmcnt(3)"  ::: "memory");
    __builtin_amdgcn_sched_barrier(0);
    __builtin_amdgcn_s_barrier();
    __builtin_amdgcn_sched_barrier(0);
    const f16* buf = hal + (s & 1) * BUFH;
    load_A(s, 1, IC<(1 + P) & 1>{});
    group_compute(buf, 0, IC<P>{});
    load_A(s, 2, IC<P>{});
    group_compute(buf, 1, IC<(1 + P) & 1>{});
    if (s + 1 < NSTAGE) {
      issue_halo(s + 1);                 // AFTER all stage-s A-loads (queue fix)
      load_A(s + 1, 0, IC<(1 + P) & 1>{});
    }
    group_compute(buf, 2, IC<P>{});
  };

  issue_halo(0);
  load_A(0, 0, IC<0>{});
  int s = 0;
  for (; s + 1 < NSTAGE; s += 2) {
    stage(s, IC<0>{});
    stage(s + 1, IC<1>{});
  }
  if (s < NSTAGE) stage(s, IC<0>{});

  // ---- epilogue ----
  if (FINAL) {
    if (kp == 0) {
      float bv = bias[0];
      #pragma unroll
      for (int nt = 0; nt < 4; ++nt) {
        int r = wave * 4 + nt;
        fout[plane * 256 + r * 16 + lm] = acc[0][nt][0] + bv;
      }
    }
  } else {
    #pragma unroll
    for (int mt = 0; mt < MT; ++mt) {
      int co = mt * 16 + kp * 4;
      const float* bp = bias + co;
      #pragma unroll
      for (int nt = 0; nt < 4; ++nt) {
        int r = wave * 4 + nt;
        f16x4 pk;
        #pragma unroll
        for (int q = 0; q < 4; ++q) {
          float v = acc[mt][nt][q] + bp[q];
          if (RELU) v = fmaxf(v, 0.f);
          pk[q] = (f16)v;
        }
        *(f16x4*)(aout + ((size_t)(plane * 256 + r * 16 + lm)) * COUTP + co) = pk;
      }
    }
  }
}

extern "C" void kernel_launch(void* const* d_in, const int* in_sizes, int n_in,
                              void* d_out, int out_size, void* d_ws, size_t ws_size,
                              hipStream_t stream)
{
  (void)in_sizes; (void)n_in; (void)out_size; (void)ws_size;
  const float* x  = (const float*)d_in[0];
  const float* w1 = (const float*)d_in[1];
  const float* b1 = (const float*)d_in[2];
  const float* w2 = (const float*)d_in[3];
  const float* b2 = (const float*)d_in[4];
  const float* w3 = (const float*)d_in[5];
  const float* b3 = (const float*)d_in[6];
  const float* w4 = (const float*)d_in[7];
  const float* b4 = (const float*)d_in[8];

  f16* ws  = (f16*)d_ws;
  f16* w1t = ws;
  f16* w2t = ws + 3072;
  f16* w3t = ws + 168960;
  f16* w4t = ws + 334848;
  f16* zpg = ws + 376320;
  f16* a1  = ws + 376448;
  f16* a2  = a1 + (size_t)2 * SP * 32;
  f16* a3  = a1;                      // a1 dead after layer 2 reads it
  float* out = (float*)d_out;

  wtrans_k<<<1471, 256, 0, stream>>>(w1, w2, w3, w4, ws);
  conv_l1_k<<<512, 256, 0, stream>>>(x, w1t, b1, a1);
  conv_plane_k<32, 64, true,  false, 2><<<512, 256, 0, stream>>>(a1, w2t, b2, zpg, a2, nullptr);
  conv_plane_k<64, 32, true,  false, 3><<<512, 256, 0, stream>>>(a2, w3t, b3, zpg, a3, nullptr);
  conv_plane_k<32, 16, false, true,  3><<<512, 256, 0, stream>>>(a3, w4t, b4, zpg, nullptr, out);
}